// Round 13
// baseline (290.826 us; speedup 1.0000x reference)
//
#include <hip/hip_runtime.h>

#define NN 100000
#define NE 3200000
#define HD 20
#define EHD 64
#define EOUTD 10
#define TBINS 1024
#define TROW 12

// ---- radix/counting sort geometry ----
#define EPB 8192
#define NBLKS1 391                 // ceil(NE/EPB)
#define NBINS1 256                 // pass-1 bins: src>>9 in [0,196)
#define N1 (NBINS1 * NBLKS1)       // 100096
#define NBUCK 196
#define WIN 4096
#define WPB 6                      // windows per bucket
#define NWIN (NBUCK * WPB)         // 1176
#define N2 (NBUCK * 512 * WPB)     // 602112

// ---------------- generic scan: per-1024-block ----------------
__global__ void scan1_kernel(int* __restrict__ data, int* __restrict__ bsum, int n) {
    __shared__ int s[1024];
    int t = threadIdx.x;
    int i = blockIdx.x * 1024 + t;
    int v = (i < n) ? data[i] : 0;
    s[t] = v;
    __syncthreads();
    for (int off = 1; off < 1024; off <<= 1) {
        int add = (t >= off) ? s[t - off] : 0;
        __syncthreads();
        s[t] += add;
        __syncthreads();
    }
    if (i < n) data[i] = s[t] - v;            // exclusive, block-local
    if (t == 1023) bsum[blockIdx.x] = s[t];
}

__global__ void scan2_kernel(int* __restrict__ bsum, int nb) {
    __shared__ int s[1024];
    int t = threadIdx.x;
    int v = (t < nb) ? bsum[t] : 0;
    s[t] = v;
    __syncthreads();
    for (int off = 1; off < 1024; off <<= 1) {
        int add = (t >= off) ? s[t - off] : 0;
        __syncthreads();
        s[t] += add;
        __syncthreads();
    }
    if (t < nb) bsum[t] = s[t] - v;           // exclusive
}

__global__ void scan3_kernel(int* __restrict__ data, const int* __restrict__ bsum, int n) {
    int i = blockIdx.x * blockDim.x + threadIdx.x;
    if (i < n) data[i] += bsum[i >> 10];
}

// ---------------- pass 1 histogram (bin = src>>9) ----------------
__global__ void hist1_kernel(const int* __restrict__ ei, int* __restrict__ counts1) {
    __shared__ int h[NBINS1];
    int t = threadIdx.x;
    h[t] = 0;
    __syncthreads();
    int base = blockIdx.x * EPB;
    for (int j = t; j < EPB; j += 256) {
        int e = base + j;
        if (e < NE) atomicAdd(&h[ei[e] >> 9], 1);
    }
    __syncthreads();
    counts1[t * NBLKS1 + blockIdx.x] = h[t];     // bin-major
}

// ---------------- pass 1 scatter (unstable, LDS cursors) ----------------
__global__ void scatter1_kernel(const int* __restrict__ ei,
                                const float* __restrict__ ea,
                                const int* __restrict__ counts1s,
                                unsigned short* __restrict__ key1,
                                int2* __restrict__ pk1) {
    __shared__ int cur[NBINS1];
    int t = threadIdx.x;
    cur[t] = counts1s[t * NBLKS1 + blockIdx.x];
    __syncthreads();
    int base = blockIdx.x * EPB;
    for (int j = t; j < EPB; j += 256) {
        int e = base + j;
        if (e >= NE) break;
        int src = ei[e];
        int pos = atomicAdd(&cur[src >> 9], 1);
        key1[pos] = (unsigned short)(src & 511);
        int2 pk;
        pk.x = ei[NE + e];
        pk.y = __float_as_int(ea[e]);
        pk1[pos] = pk;
    }
}

// ---------------- pass 2 histogram ----------------
__global__ void hist2_kernel(const unsigned short* __restrict__ key1,
                             const int* __restrict__ counts1s,
                             int* __restrict__ M2) {
    __shared__ int h[512];
    int t = threadIdx.x;
    h[t] = 0; h[t + 256] = 0;
    __syncthreads();
    int b = blockIdx.x / WPB, w = blockIdx.x % WPB;
    int bstart = counts1s[b * NBLKS1];
    int bend   = counts1s[(b + 1) * NBLKS1];
    int start = bstart + w * WIN;
    int end = (start + WIN < bend) ? (start + WIN) : bend;
    for (int i = start + t; i < end; i += 256) atomicAdd(&h[key1[i]], 1);
    __syncthreads();
    M2[((b * 512) + t) * WPB + w]       = h[t];
    M2[((b * 512) + t + 256) * WPB + w] = h[t + 256];
}

// ---------------- pass 2 scatter (final positions) ----------------
__global__ void scatter2_kernel(const unsigned short* __restrict__ key1,
                                const int2* __restrict__ pk1,
                                const int* __restrict__ counts1s,
                                const int* __restrict__ M2s,
                                int2* __restrict__ csr_pk) {
    __shared__ int cur[512];
    int t = threadIdx.x;
    int b = blockIdx.x / WPB, w = blockIdx.x % WPB;
    cur[t]       = M2s[((b * 512) + t) * WPB + w];
    cur[t + 256] = M2s[((b * 512) + t + 256) * WPB + w];
    __syncthreads();
    int bstart = counts1s[b * NBLKS1];
    int bend   = counts1s[(b + 1) * NBLKS1];
    int start = bstart + w * WIN;
    int end = (start + WIN < bend) ? (start + WIN) : bend;
    for (int i = start + t; i < end; i += 256) {
        int pos = atomicAdd(&cur[key1[i]], 1);
        csr_pk[pos] = pk1[i];
    }
}

// ---------------- offsets from scanned M2 ----------------
__global__ void offs_kernel(const int* __restrict__ M2s, int* __restrict__ offsets) {
    int n = blockIdx.x * blockDim.x + threadIdx.x;
    if (n > NN) return;
    if (n == NN) { offsets[NN] = NE; return; }
    int b = n >> 9, bin = n & 511;
    offsets[n] = M2s[((b * 512) + bin) * WPB + 0];
}

// ---------------- MLP table ----------------
__global__ void table_kernel(const float* __restrict__ W1,
                             const float* __restrict__ b1,
                             const float* __restrict__ W2,
                             const float* __restrict__ b2,
                             float* __restrict__ tab) {
    int i = blockIdx.x * blockDim.x + threadIdx.x;
    if (i > TBINS) return;
    float d = (float)i * (10.0f / (float)TBINS);
    float m[EOUTD];
    #pragma unroll
    for (int j = 0; j < EOUTD; ++j) m[j] = b2[j];
    for (int k = 0; k < EHD; ++k) {
        float h = fmaxf(fmaf(d, W1[k], b1[k]), 0.0f);
        #pragma unroll
        for (int j = 0; j < EOUTD; ++j) m[j] = fmaf(h, W2[k * EOUTD + j], m[j]);
    }
    float* row = tab + (size_t)i * TROW;
    #pragma unroll
    for (int j = 0; j < EOUTD; ++j) row[j] = m[j];
    row[10] = 0.0f; row[11] = 0.0f;
}

// ---------------- bf16-pack x[:,0,:] into 64B line-aligned rows ----------
__global__ void xbf_kernel(const float* __restrict__ x,
                           unsigned short* __restrict__ xbf) {
    int t = blockIdx.x * blockDim.x + threadIdx.x;
    if (t >= NN * 16) return;
    int node = t >> 4;
    int j = (t & 15) * 2;
    float f0 = (j < HD)     ? x[(size_t)node * 2 * HD + j]     : 0.0f;
    float f1 = (j + 1 < HD) ? x[(size_t)node * 2 * HD + j + 1] : 0.0f;
    unsigned int u0 = __float_as_uint(f0);
    unsigned int u1 = __float_as_uint(f1);
    u0 = (u0 + 0x7fffu + ((u0 >> 16) & 1u)) >> 16;   // RNE bf16
    u1 = (u1 + 0x7fffu + ((u1 >> 16) & 1u)) >> 16;
    ushort2 p;
    p.x = (unsigned short)u0;
    p.y = (unsigned short)u1;
    *(ushort2*)(xbf + (size_t)node * 32 + j) = p;
}

// ---------------- node-owner kernel: LDS table + raw transcendentals -------
__launch_bounds__(512)
__global__ void node_kernel(const int* __restrict__ offsets,
                            const int2* __restrict__ csr_pk,
                            const float* __restrict__ x,
                            const unsigned short* __restrict__ xbf,
                            const float* __restrict__ tab,
                            const float* __restrict__ pa,
                            const float* __restrict__ pb,
                            const float* __restrict__ g1,
                            const float* __restrict__ g2,
                            const float* __restrict__ bias,
                            float* __restrict__ out) {
    __shared__ float stab[(TBINS + 1) * TROW];   // 49.2 KB
    int tid  = threadIdx.x;
    // cooperative LDS fill (coalesced float4)
    {
        const float4* src4 = (const float4*)tab;
        float4* dst4 = (float4*)stab;
        const int n4 = (TBINS + 1) * TROW / 4;   // 3075
        for (int i = tid; i < n4; i += 512) dst4[i] = src4[i];
    }
    __syncthreads();

    int grp  = tid >> 4;          // 32 nodes per 512-thread block
    int lane = tid & 15;
    int node = blockIdx.x * 32 + grp;
    if (node >= NN) return;

    int off0 = offsets[node];
    int deg  = offsets[node + 1] - off0;
    float a = pa[0], bb = pb[0];
    float oma = 1.0f - a;

    float xs[HD], axs[HD];
    {
        const float4* xp = (const float4*)(x + (size_t)node * 2 * HD);
        #pragma unroll
        for (int q = 0; q < 5; ++q) {
            float4 v = xp[q];
            xs[4 * q] = v.x; xs[4 * q + 1] = v.y;
            xs[4 * q + 2] = v.z; xs[4 * q + 3] = v.w;
            axs[4 * q] = a * v.x; axs[4 * q + 1] = a * v.y;
            axs[4 * q + 2] = a * v.z; axs[4 * q + 3] = a * v.w;
        }
    }

    float S0[HD], S1[HD], Sr[HD];
    #pragma unroll
    for (int k = 0; k < HD; ++k) { S0[k] = 0.0f; S1[k] = 0.0f; Sr[k] = 0.0f; }

    auto edge = [&](float d, int4 w0, int4 w1, int4 w2) {
        float u = d * ((float)TBINS / 10.0f);
        int ti = (int)u; if (ti > TBINS - 1) ti = TBINS - 1;
        float fr = u - (float)ti;
        const float4* t0 = (const float4*)(stab + ti * TROW);
        float4 a0 = t0[0], a1 = t0[1], a2 = t0[2];
        float4 c0 = t0[3], c1 = t0[4], c2 = t0[5];
        float m[EOUTD];
        m[0] = fmaf(fr, c0.x - a0.x, a0.x);
        m[1] = fmaf(fr, c0.y - a0.y, a0.y);
        m[2] = fmaf(fr, c0.z - a0.z, a0.z);
        m[3] = fmaf(fr, c0.w - a0.w, a0.w);
        m[4] = fmaf(fr, c1.x - a1.x, a1.x);
        m[5] = fmaf(fr, c1.y - a1.y, a1.y);
        m[6] = fmaf(fr, c1.z - a1.z, a1.z);
        m[7] = fmaf(fr, c1.w - a1.w, a1.w);
        m[8] = fmaf(fr, c2.x - a2.x, a2.x);
        m[9] = fmaf(fr, c2.y - a2.y, a2.y);
        int idx = (int)d; if (idx > 9) idx = 9;

        int w[5];
        w[0] = w0.x; w[1] = w0.y; w[2] = w0.z; w[3] = w0.w;
        w[4] = w1.x;
        int w5 = w1.y;
        #pragma unroll
        for (int p = 0; p < 5; ++p) {
            int wp = w[p];
            float xlo = __uint_as_float(((unsigned int)wp) << 16);
            float xhi = __uint_as_float(((unsigned int)wp) & 0xffff0000u);
            #pragma unroll
            for (int h = 0; h < 2; ++h) {
                const int k = 2 * p + h;
                float xdk = h ? xhi : xlo;
                float t = fmaf(-oma, xdk, axs[k]);
                float rho = (t != 0.0f)
                    ? __builtin_amdgcn_exp2f(bb * __builtin_amdgcn_logf(fabsf(t)))
                    : 0.0f;
                Sr[k] += rho;
                float comb = (k == idx) ? 1.0f : 0.0f;
                S0[k] += comb;
                S1[k] = fmaf(rho, comb, S1[k]);
            }
        }
        {
            float xlo = __uint_as_float(((unsigned int)w5) << 16);
            float xhi = __uint_as_float(((unsigned int)w5) & 0xffff0000u);
            #pragma unroll
            for (int h = 0; h < 2; ++h) {
                const int k = 10 + h;
                float xdk = h ? xhi : xlo;
                float t = fmaf(-oma, xdk, axs[k]);
                float rho = (t != 0.0f)
                    ? __builtin_amdgcn_exp2f(bb * __builtin_amdgcn_logf(fabsf(t)))
                    : 0.0f;
                Sr[k] += rho;
                float comb = fmaxf(m[k - 10], 0.0f);
                S0[k] += comb;
                S1[k] = fmaf(rho, comb, S1[k]);
            }
        }
        int w6[4];
        w6[0] = w1.z; w6[1] = w1.w; w6[2] = w2.x; w6[3] = w2.y;
        #pragma unroll
        for (int p = 0; p < 4; ++p) {
            int wp = w6[p];
            float xlo = __uint_as_float(((unsigned int)wp) << 16);
            float xhi = __uint_as_float(((unsigned int)wp) & 0xffff0000u);
            #pragma unroll
            for (int h = 0; h < 2; ++h) {
                const int k = 12 + 2 * p + h;
                float xdk = h ? xhi : xlo;
                float t = fmaf(-oma, xdk, axs[k]);
                float rho = (t != 0.0f)
                    ? __builtin_amdgcn_exp2f(bb * __builtin_amdgcn_logf(fabsf(t)))
                    : 0.0f;
                Sr[k] += rho;
                float comb = fmaxf(m[k - 10], 0.0f);
                S0[k] += comb;
                S1[k] = fmaf(rho, comb, S1[k]);
            }
        }
    };

    {
        bool v0 = lane < deg;
        bool v1 = lane + 16 < deg;
        int p0 = v0 ? (off0 + lane) : off0;
        int p1 = v1 ? (off0 + lane + 16) : off0;
        if (p0 > NE - 1) p0 = NE - 1;
        if (p1 > NE - 1) p1 = NE - 1;
        int2 pk0 = csr_pk[p0];
        int2 pk1 = csr_pk[p1];
        const int4* r0 = (const int4*)(xbf + (size_t)(unsigned int)pk0.x * 32);
        const int4* r1 = (const int4*)(xbf + (size_t)(unsigned int)pk1.x * 32);
        int4 A0 = r0[0], A1 = r0[1], A2 = r0[2];
        int4 B0 = r1[0], B1 = r1[1], B2 = r1[2];
        if (v0) edge(__int_as_float(pk0.y), A0, A1, A2);
        if (v1) edge(__int_as_float(pk1.y), B0, B1, B2);
    }
    for (int i = lane + 32; i < deg; i += 16) {
        int2 pk = csr_pk[off0 + i];
        const int4* r = (const int4*)(xbf + (size_t)(unsigned int)pk.x * 32);
        int4 A0 = r[0], A1 = r[1], A2 = r[2];
        edge(__int_as_float(pk.y), A0, A1, A2);
    }

    #pragma unroll
    for (int s = 8; s >= 1; s >>= 1) {
        #pragma unroll
        for (int k = 0; k < HD; ++k) {
            S0[k] += __shfl_xor(S0[k], s, 16);
            S1[k] += __shfl_xor(S1[k], s, 16);
            Sr[k] += __shfl_xor(Sr[k], s, 16);
        }
    }

    float sf[HD];
    #pragma unroll
    for (int k = 0; k < HD; ++k)
        sf[k] = (S0[k] != 0.0f) ? (S1[k] / S0[k]) : (0.01f * Sr[k]);

    float* op = out + (size_t)node * 2 * HD;
    {
        int r = lane;
        float acc = bias[r];
        const float4* g1p = (const float4*)(g1 + r * HD);
        const float4* g2p = (const float4*)(g2 + r * HD);
        #pragma unroll
        for (int q = 0; q < 5; ++q) {
            float4 w1 = g1p[q], w2 = g2p[q];
            acc = fmaf(xs[4 * q], w1.x, acc); acc = fmaf(sf[4 * q], w2.x, acc);
            acc = fmaf(xs[4 * q + 1], w1.y, acc); acc = fmaf(sf[4 * q + 1], w2.y, acc);
            acc = fmaf(xs[4 * q + 2], w1.z, acc); acc = fmaf(sf[4 * q + 2], w2.z, acc);
            acc = fmaf(xs[4 * q + 3], w1.w, acc); acc = fmaf(sf[4 * q + 3], w2.w, acc);
        }
        float myv = 0.0f;
        #pragma unroll
        for (int k = 0; k < HD; ++k) if (r == k) myv = sf[k];
        op[r] = fmaxf(acc, 0.0f);
        op[HD + r] = myv;
    }
    if (lane < HD - 16) {
        int r = lane + 16;
        float acc = bias[r];
        const float4* g1p = (const float4*)(g1 + r * HD);
        const float4* g2p = (const float4*)(g2 + r * HD);
        #pragma unroll
        for (int q = 0; q < 5; ++q) {
            float4 w1 = g1p[q], w2 = g2p[q];
            acc = fmaf(xs[4 * q], w1.x, acc); acc = fmaf(sf[4 * q], w2.x, acc);
            acc = fmaf(xs[4 * q + 1], w1.y, acc); acc = fmaf(sf[4 * q + 1], w2.y, acc);
            acc = fmaf(xs[4 * q + 2], w1.z, acc); acc = fmaf(sf[4 * q + 2], w2.z, acc);
            acc = fmaf(xs[4 * q + 3], w1.w, acc); acc = fmaf(sf[4 * q + 3], w2.w, acc);
        }
        float myv = 0.0f;
        #pragma unroll
        for (int k = 0; k < HD; ++k) if (r == k) myv = sf[k];
        op[r] = fmaxf(acc, 0.0f);
        op[HD + r] = myv;
    }
}

extern "C" void kernel_launch(void* const* d_in, const int* in_sizes, int n_in,
                              void* d_out, int out_size, void* d_ws, size_t ws_size,
                              hipStream_t stream) {
    const float* x    = (const float*)d_in[0];
    const int*   ei   = (const int*)d_in[1];
    const float* ea   = (const float*)d_in[2];
    const float* pa   = (const float*)d_in[3];
    const float* pb   = (const float*)d_in[4];
    const float* g1   = (const float*)d_in[5];
    const float* g2   = (const float*)d_in[6];
    const float* bias = (const float*)d_in[7];
    const float* W1   = (const float*)d_in[8];
    const float* b1   = (const float*)d_in[9];
    const float* W2   = (const float*)d_in[10];
    const float* b2   = (const float*)d_in[11];
    float* out = (float*)d_out;

    // workspace layout (all segments 128B-aligned)
    char* ws = (char*)d_ws;
    int*   counts1 = (int*)ws;     ws += ((size_t)N1 * 4 + 127) / 128 * 128;
    int*   bsum1   = (int*)ws;     ws += (1024 * 4 + 127) / 128 * 128;
    int*   M2      = (int*)ws;     ws += ((size_t)N2 * 4 + 127) / 128 * 128;
    int*   bsum2   = (int*)ws;     ws += (1024 * 4 + 127) / 128 * 128;
    int*   offsets = (int*)ws;     ws += ((size_t)(NN + 1) * 4 + 127) / 128 * 128;
    unsigned short* key1 = (unsigned short*)ws;  ws += ((size_t)NE * 2 + 127) / 128 * 128;
    int2*  pk1     = (int2*)ws;    ws += (size_t)NE * 8;
    int2*  csr_pk  = (int2*)ws;    ws += (size_t)NE * 8;
    float* tab     = (float*)ws;   ws += (size_t)(TBINS + 2) * TROW * 4;
    unsigned short* xbf = (unsigned short*)ws;   ws += (size_t)NN * 32 * 2;

    table_kernel<<<(TBINS + 256) / 256, 256, 0, stream>>>(W1, b1, W2, b2, tab);
    xbf_kernel<<<(NN * 16 + 255) / 256, 256, 0, stream>>>(x, xbf);

    // pass 1: group by bucket (src>>9)
    hist1_kernel<<<NBLKS1, 256, 0, stream>>>(ei, counts1);
    scan1_kernel<<<(N1 + 1023) / 1024, 1024, 0, stream>>>(counts1, bsum1, N1);
    scan2_kernel<<<1, 1024, 0, stream>>>(bsum1, (N1 + 1023) / 1024);
    scan3_kernel<<<(N1 + 255) / 256, 256, 0, stream>>>(counts1, bsum1, N1);
    scatter1_kernel<<<NBLKS1, 256, 0, stream>>>(ei, ea, counts1, key1, pk1);

    // pass 2: within bucket, bin = src & 511 (== exact node)
    hist2_kernel<<<NWIN, 256, 0, stream>>>(key1, counts1, M2);
    scan1_kernel<<<(N2 + 1023) / 1024, 1024, 0, stream>>>(M2, bsum2, N2);
    scan2_kernel<<<1, 1024, 0, stream>>>(bsum2, (N2 + 1023) / 1024);
    scan3_kernel<<<(N2 + 255) / 256, 256, 0, stream>>>(M2, bsum2, N2);
    scatter2_kernel<<<NWIN, 256, 0, stream>>>(key1, pk1, counts1, M2, csr_pk);

    offs_kernel<<<(NN + 256) / 256, 256, 0, stream>>>(M2, offsets);

    node_kernel<<<(NN + 31) / 32, 512, 0, stream>>>(offsets, csr_pk, x, xbf, tab,
                                                    pa, pb, g1, g2, bias, out);
}

// Round 14
// 245.860 us; speedup vs baseline: 1.1829x; 1.1829x over previous
//
#include <hip/hip_runtime.h>

#define NN 100000
#define NE 3200000
#define HD 20
#define EHD 64
#define EOUTD 10
#define TBINS 4096
#define TROW 12

// ---- radix/counting sort geometry ----
#define EPB 8192
#define NBLKS1 391                 // ceil(NE/EPB)
#define NBINS1 256                 // pass-1 bins: src>>9 in [0,196)
#define N1 (NBINS1 * NBLKS1)       // 100096
#define NBUCK 196
#define WIN 4096
#define WPB 6                      // windows per bucket
#define NWIN (NBUCK * WPB)         // 1176
#define N2 (NBUCK * 512 * WPB)     // 602112

// ---------------- generic scan: per-1024-block ----------------
__global__ void scan1_kernel(int* __restrict__ data, int* __restrict__ bsum, int n) {
    __shared__ int s[1024];
    int t = threadIdx.x;
    int i = blockIdx.x * 1024 + t;
    int v = (i < n) ? data[i] : 0;
    s[t] = v;
    __syncthreads();
    for (int off = 1; off < 1024; off <<= 1) {
        int add = (t >= off) ? s[t - off] : 0;
        __syncthreads();
        s[t] += add;
        __syncthreads();
    }
    if (i < n) data[i] = s[t] - v;            // exclusive, block-local
    if (t == 1023) bsum[blockIdx.x] = s[t];
}

__global__ void scan2_kernel(int* __restrict__ bsum, int nb) {
    __shared__ int s[1024];
    int t = threadIdx.x;
    int v = (t < nb) ? bsum[t] : 0;
    s[t] = v;
    __syncthreads();
    for (int off = 1; off < 1024; off <<= 1) {
        int add = (t >= off) ? s[t - off] : 0;
        __syncthreads();
        s[t] += add;
        __syncthreads();
    }
    if (t < nb) bsum[t] = s[t] - v;           // exclusive
}

__global__ void scan3_kernel(int* __restrict__ data, const int* __restrict__ bsum, int n) {
    int i = blockIdx.x * blockDim.x + threadIdx.x;
    if (i < n) data[i] += bsum[i >> 10];
}

// ---------------- pass 1 histogram (bin = src>>9) ----------------
__global__ void hist1_kernel(const int* __restrict__ ei, int* __restrict__ counts1) {
    __shared__ int h[NBINS1];
    int t = threadIdx.x;
    h[t] = 0;
    __syncthreads();
    int base = blockIdx.x * EPB;
    for (int j = t; j < EPB; j += 256) {
        int e = base + j;
        if (e < NE) atomicAdd(&h[ei[e] >> 9], 1);
    }
    __syncthreads();
    counts1[t * NBLKS1 + blockIdx.x] = h[t];     // bin-major
}

// ---------------- pass 1 scatter (unstable, LDS cursors) ----------------
__global__ void scatter1_kernel(const int* __restrict__ ei,
                                const float* __restrict__ ea,
                                const int* __restrict__ counts1s,
                                unsigned short* __restrict__ key1,
                                int2* __restrict__ pk1) {
    __shared__ int cur[NBINS1];
    int t = threadIdx.x;
    cur[t] = counts1s[t * NBLKS1 + blockIdx.x];
    __syncthreads();
    int base = blockIdx.x * EPB;
    for (int j = t; j < EPB; j += 256) {
        int e = base + j;
        if (e >= NE) break;
        int src = ei[e];
        int pos = atomicAdd(&cur[src >> 9], 1);
        key1[pos] = (unsigned short)(src & 511);
        int2 pk;
        pk.x = ei[NE + e];
        pk.y = __float_as_int(ea[e]);
        pk1[pos] = pk;
    }
}

// ---------------- pass 2 histogram ----------------
__global__ void hist2_kernel(const unsigned short* __restrict__ key1,
                             const int* __restrict__ counts1s,
                             int* __restrict__ M2) {
    __shared__ int h[512];
    int t = threadIdx.x;
    h[t] = 0; h[t + 256] = 0;
    __syncthreads();
    int b = blockIdx.x / WPB, w = blockIdx.x % WPB;
    int bstart = counts1s[b * NBLKS1];
    int bend   = counts1s[(b + 1) * NBLKS1];
    int start = bstart + w * WIN;
    int end = (start + WIN < bend) ? (start + WIN) : bend;
    for (int i = start + t; i < end; i += 256) atomicAdd(&h[key1[i]], 1);
    __syncthreads();
    M2[((b * 512) + t) * WPB + w]       = h[t];
    M2[((b * 512) + t + 256) * WPB + w] = h[t + 256];
}

// ---------------- pass 2 scatter (final positions) ----------------
__global__ void scatter2_kernel(const unsigned short* __restrict__ key1,
                                const int2* __restrict__ pk1,
                                const int* __restrict__ counts1s,
                                const int* __restrict__ M2s,
                                int2* __restrict__ csr_pk) {
    __shared__ int cur[512];
    int t = threadIdx.x;
    int b = blockIdx.x / WPB, w = blockIdx.x % WPB;
    cur[t]       = M2s[((b * 512) + t) * WPB + w];
    cur[t + 256] = M2s[((b * 512) + t + 256) * WPB + w];
    __syncthreads();
    int bstart = counts1s[b * NBLKS1];
    int bend   = counts1s[(b + 1) * NBLKS1];
    int start = bstart + w * WIN;
    int end = (start + WIN < bend) ? (start + WIN) : bend;
    for (int i = start + t; i < end; i += 256) {
        int pos = atomicAdd(&cur[key1[i]], 1);
        csr_pk[pos] = pk1[i];
    }
}

// ---------------- offsets from scanned M2 ----------------
__global__ void offs_kernel(const int* __restrict__ M2s, int* __restrict__ offsets) {
    int n = blockIdx.x * blockDim.x + threadIdx.x;
    if (n > NN) return;
    if (n == NN) { offsets[NN] = NE; return; }
    int b = n >> 9, bin = n & 511;
    offsets[n] = M2s[((b * 512) + bin) * WPB + 0];
}

// ---------------- MLP table ----------------
__global__ void table_kernel(const float* __restrict__ W1,
                             const float* __restrict__ b1,
                             const float* __restrict__ W2,
                             const float* __restrict__ b2,
                             float* __restrict__ tab) {
    int i = blockIdx.x * blockDim.x + threadIdx.x;
    if (i > TBINS) return;
    float d = (float)i * (10.0f / (float)TBINS);
    float m[EOUTD];
    #pragma unroll
    for (int j = 0; j < EOUTD; ++j) m[j] = b2[j];
    for (int k = 0; k < EHD; ++k) {
        float h = fmaxf(fmaf(d, W1[k], b1[k]), 0.0f);
        #pragma unroll
        for (int j = 0; j < EOUTD; ++j) m[j] = fmaf(h, W2[k * EOUTD + j], m[j]);
    }
    float* row = tab + (size_t)i * TROW;
    #pragma unroll
    for (int j = 0; j < EOUTD; ++j) row[j] = m[j];
    row[10] = 0.0f; row[11] = 0.0f;
}

// ---------------- bf16-pack x[:,0,:] into 64B line-aligned rows ----------
__global__ void xbf_kernel(const float* __restrict__ x,
                           unsigned short* __restrict__ xbf) {
    int t = blockIdx.x * blockDim.x + threadIdx.x;
    if (t >= NN * 16) return;
    int node = t >> 4;
    int j = (t & 15) * 2;
    float f0 = (j < HD)     ? x[(size_t)node * 2 * HD + j]     : 0.0f;
    float f1 = (j + 1 < HD) ? x[(size_t)node * 2 * HD + j + 1] : 0.0f;
    unsigned int u0 = __float_as_uint(f0);
    unsigned int u1 = __float_as_uint(f1);
    u0 = (u0 + 0x7fffu + ((u0 >> 16) & 1u)) >> 16;   // RNE bf16
    u1 = (u1 + 0x7fffu + ((u1 >> 16) & 1u)) >> 16;
    ushort2 p;
    p.x = (unsigned short)u0;
    p.y = (unsigned short)u1;
    *(ushort2*)(xbf + (size_t)node * 32 + j) = p;
}

// ---------------- node-owner kernel: R12 structure + raw transcendentals ---
__launch_bounds__(256)
__global__ void node_kernel(const int* __restrict__ offsets,
                            const int2* __restrict__ csr_pk,
                            const float* __restrict__ x,
                            const unsigned short* __restrict__ xbf,
                            const float* __restrict__ tab,
                            const float* __restrict__ pa,
                            const float* __restrict__ pb,
                            const float* __restrict__ g1,
                            const float* __restrict__ g2,
                            const float* __restrict__ bias,
                            float* __restrict__ out) {
    int tid  = threadIdx.x;
    int grp  = tid >> 4;          // 16 nodes per 256-thread block
    int lane = tid & 15;
    int node = blockIdx.x * 16 + grp;
    if (node >= NN) return;

    int off0 = offsets[node];
    int deg  = offsets[node + 1] - off0;
    float a = pa[0], bb = pb[0];
    float oma = 1.0f - a;

    float xs[HD], axs[HD];
    {
        const float4* xp = (const float4*)(x + (size_t)node * 2 * HD);
        #pragma unroll
        for (int q = 0; q < 5; ++q) {
            float4 v = xp[q];
            xs[4 * q] = v.x; xs[4 * q + 1] = v.y;
            xs[4 * q + 2] = v.z; xs[4 * q + 3] = v.w;
            axs[4 * q] = a * v.x; axs[4 * q + 1] = a * v.y;
            axs[4 * q + 2] = a * v.z; axs[4 * q + 3] = a * v.w;
        }
    }

    float S0[HD], S1[HD], Sr[HD];
    #pragma unroll
    for (int k = 0; k < HD; ++k) { S0[k] = 0.0f; S1[k] = 0.0f; Sr[k] = 0.0f; }

    auto edge = [&](float d, int4 w0, int4 w1, int4 w2) {
        float u = d * ((float)TBINS / 10.0f);
        int ti = (int)u; if (ti > TBINS - 1) ti = TBINS - 1;
        float fr = u - (float)ti;
        const float4* t0 = (const float4*)(tab + (size_t)ti * TROW);
        float4 a0 = t0[0], a1 = t0[1], a2 = t0[2];
        float4 c0 = t0[3], c1 = t0[4], c2 = t0[5];
        float m[EOUTD];
        m[0] = fmaf(fr, c0.x - a0.x, a0.x);
        m[1] = fmaf(fr, c0.y - a0.y, a0.y);
        m[2] = fmaf(fr, c0.z - a0.z, a0.z);
        m[3] = fmaf(fr, c0.w - a0.w, a0.w);
        m[4] = fmaf(fr, c1.x - a1.x, a1.x);
        m[5] = fmaf(fr, c1.y - a1.y, a1.y);
        m[6] = fmaf(fr, c1.z - a1.z, a1.z);
        m[7] = fmaf(fr, c1.w - a1.w, a1.w);
        m[8] = fmaf(fr, c2.x - a2.x, a2.x);
        m[9] = fmaf(fr, c2.y - a2.y, a2.y);
        int idx = (int)d; if (idx > 9) idx = 9;

        int w[5];
        w[0] = w0.x; w[1] = w0.y; w[2] = w0.z; w[3] = w0.w;
        w[4] = w1.x;
        int w5 = w1.y;
        #pragma unroll
        for (int p = 0; p < 5; ++p) {
            int wp = w[p];
            float xlo = __uint_as_float(((unsigned int)wp) << 16);
            float xhi = __uint_as_float(((unsigned int)wp) & 0xffff0000u);
            #pragma unroll
            for (int h = 0; h < 2; ++h) {
                const int k = 2 * p + h;
                float xdk = h ? xhi : xlo;
                float t = fmaf(-oma, xdk, axs[k]);
                float rho = (t != 0.0f)
                    ? __builtin_amdgcn_exp2f(bb * __builtin_amdgcn_logf(fabsf(t)))
                    : 0.0f;
                Sr[k] += rho;
                float comb = (k == idx) ? 1.0f : 0.0f;
                S0[k] += comb;
                S1[k] = fmaf(rho, comb, S1[k]);
            }
        }
        {
            float xlo = __uint_as_float(((unsigned int)w5) << 16);
            float xhi = __uint_as_float(((unsigned int)w5) & 0xffff0000u);
            #pragma unroll
            for (int h = 0; h < 2; ++h) {
                const int k = 10 + h;
                float xdk = h ? xhi : xlo;
                float t = fmaf(-oma, xdk, axs[k]);
                float rho = (t != 0.0f)
                    ? __builtin_amdgcn_exp2f(bb * __builtin_amdgcn_logf(fabsf(t)))
                    : 0.0f;
                Sr[k] += rho;
                float comb = fmaxf(m[k - 10], 0.0f);
                S0[k] += comb;
                S1[k] = fmaf(rho, comb, S1[k]);
            }
        }
        int w6[4];
        w6[0] = w1.z; w6[1] = w1.w; w6[2] = w2.x; w6[3] = w2.y;
        #pragma unroll
        for (int p = 0; p < 4; ++p) {
            int wp = w6[p];
            float xlo = __uint_as_float(((unsigned int)wp) << 16);
            float xhi = __uint_as_float(((unsigned int)wp) & 0xffff0000u);
            #pragma unroll
            for (int h = 0; h < 2; ++h) {
                const int k = 12 + 2 * p + h;
                float xdk = h ? xhi : xlo;
                float t = fmaf(-oma, xdk, axs[k]);
                float rho = (t != 0.0f)
                    ? __builtin_amdgcn_exp2f(bb * __builtin_amdgcn_logf(fabsf(t)))
                    : 0.0f;
                Sr[k] += rho;
                float comb = fmaxf(m[k - 10], 0.0f);
                S0[k] += comb;
                S1[k] = fmaf(rho, comb, S1[k]);
            }
        }
    };

    {
        bool v0 = lane < deg;
        bool v1 = lane + 16 < deg;
        int p0 = v0 ? (off0 + lane) : off0;
        int p1 = v1 ? (off0 + lane + 16) : off0;
        if (p0 > NE - 1) p0 = NE - 1;
        if (p1 > NE - 1) p1 = NE - 1;
        int2 pk0 = csr_pk[p0];
        int2 pk1 = csr_pk[p1];
        const int4* r0 = (const int4*)(xbf + (size_t)(unsigned int)pk0.x * 32);
        const int4* r1 = (const int4*)(xbf + (size_t)(unsigned int)pk1.x * 32);
        int4 A0 = r0[0], A1 = r0[1], A2 = r0[2];
        int4 B0 = r1[0], B1 = r1[1], B2 = r1[2];
        if (v0) edge(__int_as_float(pk0.y), A0, A1, A2);
        if (v1) edge(__int_as_float(pk1.y), B0, B1, B2);
    }
    for (int i = lane + 32; i < deg; i += 16) {
        int2 pk = csr_pk[off0 + i];
        const int4* r = (const int4*)(xbf + (size_t)(unsigned int)pk.x * 32);
        int4 A0 = r[0], A1 = r[1], A2 = r[2];
        edge(__int_as_float(pk.y), A0, A1, A2);
    }

    #pragma unroll
    for (int s = 8; s >= 1; s >>= 1) {
        #pragma unroll
        for (int k = 0; k < HD; ++k) {
            S0[k] += __shfl_xor(S0[k], s, 16);
            S1[k] += __shfl_xor(S1[k], s, 16);
            Sr[k] += __shfl_xor(Sr[k], s, 16);
        }
    }

    float sf[HD];
    #pragma unroll
    for (int k = 0; k < HD; ++k)
        sf[k] = (S0[k] != 0.0f) ? (S1[k] / S0[k]) : (0.01f * Sr[k]);

    float* op = out + (size_t)node * 2 * HD;
    {
        int r = lane;
        float acc = bias[r];
        const float4* g1p = (const float4*)(g1 + r * HD);
        const float4* g2p = (const float4*)(g2 + r * HD);
        #pragma unroll
        for (int q = 0; q < 5; ++q) {
            float4 w1 = g1p[q], w2 = g2p[q];
            acc = fmaf(xs[4 * q], w1.x, acc); acc = fmaf(sf[4 * q], w2.x, acc);
            acc = fmaf(xs[4 * q + 1], w1.y, acc); acc = fmaf(sf[4 * q + 1], w2.y, acc);
            acc = fmaf(xs[4 * q + 2], w1.z, acc); acc = fmaf(sf[4 * q + 2], w2.z, acc);
            acc = fmaf(xs[4 * q + 3], w1.w, acc); acc = fmaf(sf[4 * q + 3], w2.w, acc);
        }
        float myv = 0.0f;
        #pragma unroll
        for (int k = 0; k < HD; ++k) if (r == k) myv = sf[k];
        op[r] = fmaxf(acc, 0.0f);
        op[HD + r] = myv;
    }
    if (lane < HD - 16) {
        int r = lane + 16;
        float acc = bias[r];
        const float4* g1p = (const float4*)(g1 + r * HD);
        const float4* g2p = (const float4*)(g2 + r * HD);
        #pragma unroll
        for (int q = 0; q < 5; ++q) {
            float4 w1 = g1p[q], w2 = g2p[q];
            acc = fmaf(xs[4 * q], w1.x, acc); acc = fmaf(sf[4 * q], w2.x, acc);
            acc = fmaf(xs[4 * q + 1], w1.y, acc); acc = fmaf(sf[4 * q + 1], w2.y, acc);
            acc = fmaf(xs[4 * q + 2], w1.z, acc); acc = fmaf(sf[4 * q + 2], w2.z, acc);
            acc = fmaf(xs[4 * q + 3], w1.w, acc); acc = fmaf(sf[4 * q + 3], w2.w, acc);
        }
        float myv = 0.0f;
        #pragma unroll
        for (int k = 0; k < HD; ++k) if (r == k) myv = sf[k];
        op[r] = fmaxf(acc, 0.0f);
        op[HD + r] = myv;
    }
}

extern "C" void kernel_launch(void* const* d_in, const int* in_sizes, int n_in,
                              void* d_out, int out_size, void* d_ws, size_t ws_size,
                              hipStream_t stream) {
    const float* x    = (const float*)d_in[0];
    const int*   ei   = (const int*)d_in[1];
    const float* ea   = (const float*)d_in[2];
    const float* pa   = (const float*)d_in[3];
    const float* pb   = (const float*)d_in[4];
    const float* g1   = (const float*)d_in[5];
    const float* g2   = (const float*)d_in[6];
    const float* bias = (const float*)d_in[7];
    const float* W1   = (const float*)d_in[8];
    const float* b1   = (const float*)d_in[9];
    const float* W2   = (const float*)d_in[10];
    const float* b2   = (const float*)d_in[11];
    float* out = (float*)d_out;

    // workspace layout (all segments 128B-aligned)
    char* ws = (char*)d_ws;
    int*   counts1 = (int*)ws;     ws += ((size_t)N1 * 4 + 127) / 128 * 128;
    int*   bsum1   = (int*)ws;     ws += (1024 * 4 + 127) / 128 * 128;
    int*   M2      = (int*)ws;     ws += ((size_t)N2 * 4 + 127) / 128 * 128;
    int*   bsum2   = (int*)ws;     ws += (1024 * 4 + 127) / 128 * 128;
    int*   offsets = (int*)ws;     ws += ((size_t)(NN + 1) * 4 + 127) / 128 * 128;
    unsigned short* key1 = (unsigned short*)ws;  ws += ((size_t)NE * 2 + 127) / 128 * 128;
    int2*  pk1     = (int2*)ws;    ws += (size_t)NE * 8;
    int2*  csr_pk  = (int2*)ws;    ws += (size_t)NE * 8;
    float* tab     = (float*)ws;   ws += (size_t)(TBINS + 2) * TROW * 4;
    unsigned short* xbf = (unsigned short*)ws;   ws += (size_t)NN * 32 * 2;

    table_kernel<<<(TBINS + 256) / 256, 256, 0, stream>>>(W1, b1, W2, b2, tab);
    xbf_kernel<<<(NN * 16 + 255) / 256, 256, 0, stream>>>(x, xbf);

    // pass 1: group by bucket (src>>9)
    hist1_kernel<<<NBLKS1, 256, 0, stream>>>(ei, counts1);
    scan1_kernel<<<(N1 + 1023) / 1024, 1024, 0, stream>>>(counts1, bsum1, N1);
    scan2_kernel<<<1, 1024, 0, stream>>>(bsum1, (N1 + 1023) / 1024);
    scan3_kernel<<<(N1 + 255) / 256, 256, 0, stream>>>(counts1, bsum1, N1);
    scatter1_kernel<<<NBLKS1, 256, 0, stream>>>(ei, ea, counts1, key1, pk1);

    // pass 2: within bucket, bin = src & 511 (== exact node)
    hist2_kernel<<<NWIN, 256, 0, stream>>>(key1, counts1, M2);
    scan1_kernel<<<(N2 + 1023) / 1024, 1024, 0, stream>>>(M2, bsum2, N2);
    scan2_kernel<<<1, 1024, 0, stream>>>(bsum2, (N2 + 1023) / 1024);
    scan3_kernel<<<(N2 + 255) / 256, 256, 0, stream>>>(M2, bsum2, N2);
    scatter2_kernel<<<NWIN, 256, 0, stream>>>(key1, pk1, counts1, M2, csr_pk);

    offs_kernel<<<(NN + 256) / 256, 256, 0, stream>>>(M2, offsets);

    node_kernel<<<(NN + 15) / 16, 256, 0, stream>>>(offsets, csr_pk, x, xbf, tab,
                                                    pa, pb, g1, g2, bias, out);
}